// Round 2
// baseline (462.038 us; speedup 1.0000x reference)
//
#include <hip/hip_runtime.h>
#include <cstdint>

typedef unsigned long long u64;

#define HWSZ 3136      // 56*56
#define WD 56
#define NPIX 50176     // 16*3136
#define NB 16

__device__ __forceinline__ float clampf(float v){ return fminf(1.0f, fmaxf(-1.0f, v)); }

// ---------------- weight prep: pack sign bits, fold bn ----------------
__global__ __launch_bounds__(256) void k_wprep(
    const float* __restrict__ w1, const float* __restrict__ w2,
    const float* __restrict__ g1, const float* __restrict__ be1,
    const float* __restrict__ m1, const float* __restrict__ v1,
    const float* __restrict__ g2, const float* __restrict__ be2,
    const float* __restrict__ m2, const float* __restrict__ v2,
    u64* __restrict__ w1b, u64* __restrict__ w2e, u64* __restrict__ w2o,
    float* __restrict__ A1, float* __restrict__ B1,
    float* __restrict__ A2, float* __restrict__ B2)
{
    int co  = blockIdx.x;
    int tid = threadIdx.x;
    int wv = tid >> 6, lane = tid & 63;
    int ci = (wv << 6) + lane;          // 0..255

    float s1 = 0.f, s2 = 0.f;
    // w1: (256,256,3,3)
    const float* w1p = w1 + ((size_t)co * 256 + ci) * 9;
#pragma unroll
    for (int t = 0; t < 9; t++) {
        float v = w1p[t];
        s1 += fabsf(v);
        u64 bal = __ballot(v >= 0.f);
        if (lane == 0) w1b[(co * 9 + t) * 4 + wv] = bal;
    }
    // w2: (256,512,3,3); even input ch = conv1 branch, odd = idle branch
    const float* wep = w2 + ((size_t)co * 512 + 2 * ci) * 9;
    const float* wop = wep + 9;
#pragma unroll
    for (int t = 0; t < 9; t++) {
        float ve = wep[t], vo = wop[t];
        s2 += fabsf(ve) + fabsf(vo);
        u64 bale = __ballot(ve >= 0.f);
        u64 balo = __ballot(vo >= 0.f);
        if (lane == 0) { w2e[(co * 9 + t) * 4 + wv] = bale; w2o[(co * 9 + t) * 4 + wv] = balo; }
    }
    __shared__ float red1[256], red2[256];
    red1[tid] = s1; red2[tid] = s2;
    __syncthreads();
    for (int off = 128; off > 0; off >>= 1) {
        if (tid < off) { red1[tid] += red1[tid + off]; red2[tid] += red2[tid + off]; }
        __syncthreads();
    }
    if (tid == 0) {
        float scale1 = red1[0] / 2304.f;
        float scale2 = red2[0] / 4608.f;
        float inv1 = g1[co] / sqrtf(v1[co] + 1e-5f);
        float inv2 = g2[co] / sqrtf(v2[co] + 1e-5f);
        A1[co] = scale1 * inv1;  B1[co] = be1[co] - m1[co] * inv1;
        A2[co] = scale2 * inv2;  B2[co] = be2[co] - m2[co] * inv2;
    }
}

// ---------------- activation packing ----------------
__global__ __launch_bounds__(256) void k_pack(
    const float* __restrict__ x, const float* __restrict__ mb,
    u64* __restrict__ bitsA, u64* __restrict__ bitsI)
{
    int tid = threadIdx.x;
    int p = blockIdx.x * 256 + tid;          // pixel (b,hw)
    int q = blockIdx.y;                       // 64-channel quarter
    int b = p / HWSZ, hw = p % HWSZ;
    const float* xa = x + ((size_t)(b * 512 + q * 64)) * HWSZ + hw;
    const float* xi = x + ((size_t)(b * 512 + 256 + q * 64)) * HWSZ + hw;
    const float* mbq = mb + q * 64;
    u64 wa = 0, wi = 0;
#pragma unroll 8
    for (int j = 0; j < 64; j++) {
        float va = xa[(size_t)j * HWSZ];
        float vi = xi[(size_t)j * HWSZ] + mbq[j];
        wa |= (u64)(va >= 0.f) << j;
        wi |= (u64)(vi >= 0.f) << j;
    }
    bitsA[(size_t)p * 4 + q] = wa;
    bitsI[(size_t)p * 4 + q] = wi;
}

// ---------------- conv1: 256->256 binary conv + bn + residual + clip ----------------
__global__ __launch_bounds__(256) void k_conv1(
    const float* __restrict__ x, const u64* __restrict__ bitsA,
    const u64* __restrict__ w1b, const float* __restrict__ A1, const float* __restrict__ B1,
    u64* __restrict__ bitsC, float* __restrict__ c1v)
{
    __shared__ u64 sw[2304];         // 64 co * 9 taps * 4 words
    __shared__ float sA[64], sB[64];
    int tid = threadIdx.x;
    int q = blockIdx.y;
    int cobase = q * 64;
    {
        const u64* src = w1b + (size_t)cobase * 36;
#pragma unroll
        for (int i = 0; i < 9; i++) sw[tid + i * 256] = src[tid + i * 256];
        if (tid < 64) { sA[tid] = A1[cobase + tid]; sB[tid] = B1[cobase + tid]; }
    }
    __syncthreads();

    int p = blockIdx.x * 256 + tid;
    int b = p / HWSZ, hw = p % HWSZ;
    int h = hw / WD, w = hw % WD;

    int acc[64];
#pragma unroll
    for (int i = 0; i < 64; i++) acc[i] = 0;
    int nvalid = 0;
#pragma unroll 1
    for (int t = 0; t < 9; t++) {
        int dy = t / 3 - 1, dx = t % 3 - 1;
        int hh = h + dy, ww = w + dx;
        bool valid = (hh >= 0 && hh < WD && ww >= 0 && ww < WD);
        u64 n0 = 0, n1 = 0, n2 = 0, n3 = 0;
        if (valid) {
            const u64* nb = bitsA + (size_t)(p + dy * WD + dx) * 4;
            n0 = nb[0]; n1 = nb[1]; n2 = nb[2]; n3 = nb[3];
        }
        int mask = valid ? -1 : 0;
        nvalid -= mask;
#pragma unroll
        for (int co = 0; co < 64; co++) {
            const u64* wp = &sw[(co * 9 + t) * 4];
            int pt = __popcll(n0 ^ wp[0]) + __popcll(n1 ^ wp[1])
                   + __popcll(n2 ^ wp[2]) + __popcll(n3 ^ wp[3]);
            acc[co] += pt & mask;
        }
    }
    // epilogue: y*A + B + residual, clip, sign-pack
    u64 signw = 0;
    const float* xr = x + ((size_t)(b * 512 + cobase)) * HWSZ + hw;
    float* cv = c1v + (size_t)cobase * NPIX + p;
#pragma unroll
    for (int co = 0; co < 64; co++) {
        int y = (nvalid << 8) - 2 * acc[co];
        float v = (float)y * sA[co] + sB[co] + xr[(size_t)co * HWSZ];
        signw |= (u64)(v >= 0.f) << co;
        if (q < 2) cv[(size_t)co * NPIX] = clampf(v);
    }
    bitsC[(size_t)p * 4 + q] = signw;
}

// ---------------- conv2: 512->256 binary conv + bn + shuffled residual + clip ----------------
__global__ __launch_bounds__(256) void k_conv2(
    const float* __restrict__ x, const float* __restrict__ mb,
    const u64* __restrict__ bitsC, const u64* __restrict__ bitsI,
    const u64* __restrict__ w2e, const u64* __restrict__ w2o,
    const float* __restrict__ A2, const float* __restrict__ B2,
    const float* __restrict__ c1v, float* __restrict__ out)
{
    __shared__ u64 se[2304], so[2304];
    __shared__ float sA[64], sB[64], sM[32];
    int tid = threadIdx.x;
    int q = blockIdx.y;
    int cobase = q * 64;
    {
        const u64* srcE = w2e + (size_t)cobase * 36;
        const u64* srcO = w2o + (size_t)cobase * 36;
#pragma unroll
        for (int i = 0; i < 9; i++) { se[tid + i * 256] = srcE[tid + i * 256]; so[tid + i * 256] = srcO[tid + i * 256]; }
        if (tid < 64) { sA[tid] = A2[cobase + tid]; sB[tid] = B2[cobase + tid]; }
        if (tid < 32) { sM[tid] = mb[cobase / 2 + tid]; }
    }
    __syncthreads();

    int p = blockIdx.x * 256 + tid;
    int b = p / HWSZ, hw = p % HWSZ;
    int h = hw / WD, w = hw % WD;

    int acc[64];
#pragma unroll
    for (int i = 0; i < 64; i++) acc[i] = 0;
    int nvalid = 0;
#pragma unroll 1
    for (int t = 0; t < 9; t++) {
        int dy = t / 3 - 1, dx = t % 3 - 1;
        int hh = h + dy, ww = w + dx;
        bool valid = (hh >= 0 && hh < WD && ww >= 0 && ww < WD);
        u64 c0 = 0, c1 = 0, c2 = 0, c3 = 0, i0 = 0, i1 = 0, i2 = 0, i3 = 0;
        if (valid) {
            size_t np = (size_t)(p + dy * WD + dx) * 4;
            c0 = bitsC[np]; c1 = bitsC[np + 1]; c2 = bitsC[np + 2]; c3 = bitsC[np + 3];
            i0 = bitsI[np]; i1 = bitsI[np + 1]; i2 = bitsI[np + 2]; i3 = bitsI[np + 3];
        }
        int mask = valid ? -1 : 0;
        nvalid -= mask;
#pragma unroll
        for (int co = 0; co < 64; co++) {
            const u64* we = &se[(co * 9 + t) * 4];
            const u64* wo = &so[(co * 9 + t) * 4];
            int pt = __popcll(c0 ^ we[0]) + __popcll(c1 ^ we[1])
                   + __popcll(c2 ^ we[2]) + __popcll(c3 ^ we[3])
                   + __popcll(i0 ^ wo[0]) + __popcll(i1 ^ wo[1])
                   + __popcll(i2 ^ wo[2]) + __popcll(i3 ^ wo[3]);
            acc[co] += pt & mask;
        }
    }
    // epilogue: residual1[coG] = even -> c1v[coG/2], odd -> x_idle[coG/2]+mb[coG/2]
    const float* xo = x + ((size_t)(b * 512 + 256 + 32 * q)) * HWSZ + hw;
    const float* cvr = c1v + (size_t)(32 * q) * NPIX + p;
    float* op = out + ((size_t)(b * 256 + cobase)) * HWSZ + hw;
#pragma unroll
    for (int co = 0; co < 64; co++) {
        int y = (nvalid << 9) - 2 * acc[co];
        float v = (float)y * sA[co] + sB[co];
        int cg2 = co >> 1;
        float res;
        if ((co & 1) == 0) res = cvr[(size_t)cg2 * NPIX];
        else               res = xo[(size_t)cg2 * HWSZ] + sM[cg2];
        v += res;
        op[(size_t)co * HWSZ] = clampf(v);
    }
}

extern "C" void kernel_launch(void* const* d_in, const int* in_sizes, int n_in,
                              void* d_out, int out_size, void* d_ws, size_t ws_size,
                              hipStream_t stream)
{
    const float* x   = (const float*)d_in[0];
    const float* w1  = (const float*)d_in[1];
    const float* w2  = (const float*)d_in[2];
    const float* g1  = (const float*)d_in[3];
    const float* be1 = (const float*)d_in[4];
    const float* m1  = (const float*)d_in[5];
    const float* v1  = (const float*)d_in[6];
    const float* g2  = (const float*)d_in[7];
    const float* be2 = (const float*)d_in[8];
    const float* m2  = (const float*)d_in[9];
    const float* v2  = (const float*)d_in[10];
    const float* mb  = (const float*)d_in[11];

    char* ws = (char*)d_ws;
    u64* w1b = (u64*)ws; ws += 73728;
    u64* w2e = (u64*)ws; ws += 73728;
    u64* w2o = (u64*)ws; ws += 73728;
    float* A1 = (float*)ws; ws += 1024;
    float* B1 = (float*)ws; ws += 1024;
    float* A2 = (float*)ws; ws += 1024;
    float* B2 = (float*)ws; ws += 1024;
    u64* bitsA = (u64*)ws; ws += (size_t)NPIX * 4 * 8;
    u64* bitsI = (u64*)ws; ws += (size_t)NPIX * 4 * 8;
    u64* bitsC = (u64*)ws; ws += (size_t)NPIX * 4 * 8;
    float* c1v = (float*)ws; ws += (size_t)128 * NPIX * 4;

    hipLaunchKernelGGL(k_wprep, dim3(256), dim3(256), 0, stream,
                       w1, w2, g1, be1, m1, v1, g2, be2, m2, v2,
                       w1b, w2e, w2o, A1, B1, A2, B2);
    hipLaunchKernelGGL(k_pack, dim3(196, 4), dim3(256), 0, stream, x, mb, bitsA, bitsI);
    hipLaunchKernelGGL(k_conv1, dim3(196, 4), dim3(256), 0, stream,
                       x, bitsA, w1b, A1, B1, bitsC, c1v);
    hipLaunchKernelGGL(k_conv2, dim3(196, 4), dim3(256), 0, stream,
                       x, mb, bitsC, bitsI, w2e, w2o, A2, B2, c1v, (float*)d_out);
}

// Round 3
// 409.815 us; speedup vs baseline: 1.1274x; 1.1274x over previous
//
#include <hip/hip_runtime.h>
#include <cstdint>

typedef unsigned long long u64;
typedef unsigned short u16;

#define HWSZ 3136      // 56*56
#define WD 56
#define NPIX 50176     // 16*3136

__device__ __forceinline__ float clampf(float v){ return fminf(1.0f, fmaxf(-1.0f, v)); }

// ---------------- weight prep: pack sign bits, fold bn ----------------
__global__ __launch_bounds__(256) void k_wprep(
    const float* __restrict__ w1, const float* __restrict__ w2,
    const float* __restrict__ g1, const float* __restrict__ be1,
    const float* __restrict__ m1, const float* __restrict__ v1,
    const float* __restrict__ g2, const float* __restrict__ be2,
    const float* __restrict__ m2, const float* __restrict__ v2,
    u64* __restrict__ w1b, u64* __restrict__ w2e, u64* __restrict__ w2o,
    float* __restrict__ A1, float* __restrict__ B1,
    float* __restrict__ A2, float* __restrict__ B2)
{
    int co  = blockIdx.x;
    int tid = threadIdx.x;
    int wv = tid >> 6, lane = tid & 63;
    int ci = (wv << 6) + lane;          // 0..255

    float s1 = 0.f, s2 = 0.f;
    const float* w1p = w1 + ((size_t)co * 256 + ci) * 9;
#pragma unroll
    for (int t = 0; t < 9; t++) {
        float v = w1p[t];
        s1 += fabsf(v);
        u64 bal = __ballot(v >= 0.f);
        if (lane == 0) w1b[(co * 9 + t) * 4 + wv] = bal;
    }
    const float* wep = w2 + ((size_t)co * 512 + 2 * ci) * 9;
    const float* wop = wep + 9;
#pragma unroll
    for (int t = 0; t < 9; t++) {
        float ve = wep[t], vo = wop[t];
        s2 += fabsf(ve) + fabsf(vo);
        u64 bale = __ballot(ve >= 0.f);
        u64 balo = __ballot(vo >= 0.f);
        if (lane == 0) { w2e[(co * 9 + t) * 4 + wv] = bale; w2o[(co * 9 + t) * 4 + wv] = balo; }
    }
    __shared__ float red1[256], red2[256];
    red1[tid] = s1; red2[tid] = s2;
    __syncthreads();
    for (int off = 128; off > 0; off >>= 1) {
        if (tid < off) { red1[tid] += red1[tid + off]; red2[tid] += red2[tid + off]; }
        __syncthreads();
    }
    if (tid == 0) {
        float scale1 = red1[0] / 2304.f;
        float scale2 = red2[0] / 4608.f;
        float inv1 = g1[co] / sqrtf(v1[co] + 1e-5f);
        float inv2 = g2[co] / sqrtf(v2[co] + 1e-5f);
        A1[co] = scale1 * inv1;  B1[co] = be1[co] - m1[co] * inv1;
        A2[co] = scale2 * inv2;  B2[co] = be2[co] - m2[co] * inv2;
    }
}

// ---------------- activation packing ----------------
__global__ __launch_bounds__(256) void k_pack(
    const float* __restrict__ x, const float* __restrict__ mb,
    u64* __restrict__ bitsA, u64* __restrict__ bitsI)
{
    int tid = threadIdx.x;
    int p = blockIdx.x * 256 + tid;          // pixel (b,hw)
    int q = blockIdx.y;                       // 64-channel quarter
    int b = p / HWSZ, hw = p % HWSZ;
    const float* xa = x + ((size_t)(b * 512 + q * 64)) * HWSZ + hw;
    const float* xi = x + ((size_t)(b * 512 + 256 + q * 64)) * HWSZ + hw;
    const float* mbq = mb + q * 64;
    u64 wa = 0, wi = 0;
#pragma unroll 8
    for (int j = 0; j < 64; j++) {
        float va = xa[(size_t)j * HWSZ];
        float vi = xi[(size_t)j * HWSZ] + mbq[j];
        wa |= (u64)(va >= 0.f) << j;
        wi |= (u64)(vi >= 0.f) << j;
    }
    bitsA[(size_t)p * 4 + q] = wa;
    bitsI[(size_t)p * 4 + q] = wi;
}

// ---------------- conv1: 256->256 binary conv + bn + residual + clip ----------------
// thread layout: wave g (0..3) owns co-group [q*64+g*16, +16); lane owns 2 adjacent pixels
__global__ __launch_bounds__(256, 4) void k_conv1(
    const float* __restrict__ x, const u64* __restrict__ bitsA,
    const u64* __restrict__ w1b, const float* __restrict__ A1, const float* __restrict__ B1,
    u64* __restrict__ bitsC, float* __restrict__ c1v)
{
    __shared__ u64 sw[2304];         // 64 co * 9 taps * 4 words
    __shared__ float sA[64], sB[64];
    __shared__ u16 spart[4][128];
    int tid = threadIdx.x;
    int q = blockIdx.y;
    int cobase = q * 64;
    {
        const u64* src = w1b + (size_t)cobase * 36;
#pragma unroll
        for (int i = 0; i < 9; i++) sw[tid + i * 256] = src[tid + i * 256];
        if (tid < 64) { sA[tid] = A1[cobase + tid]; sB[tid] = B1[cobase + tid]; }
    }
    __syncthreads();

    int g = tid >> 6, lane = tid & 63;
    int pix0 = blockIdx.x * 128 + lane * 2;
    int b = pix0 / HWSZ, hw = pix0 % HWSZ;
    int h = hw / WD, w = hw % WD;

    int acc[16][2];
#pragma unroll
    for (int co = 0; co < 16; co++) { acc[co][0] = 0; acc[co][1] = 0; }
    int nv0 = 0, nv1 = 0;

#pragma unroll 1
    for (int dy = -1; dy <= 1; dy++) {
        bool rowok = ((unsigned)(h + dy)) < (unsigned)WD;
        u64 cb[4][4];
        int m[4];
#pragma unroll
        for (int k = 0; k < 4; k++) {
            int c = w - 1 + k;
            bool ok = rowok && ((unsigned)c < (unsigned)WD);
            int pg = pix0 + dy * WD + (k - 1);
            pg = pg < 0 ? 0 : (pg > NPIX - 1 ? NPIX - 1 : pg);
            const ulonglong2* pb = (const ulonglong2*)(bitsA + (size_t)pg * 4);
            ulonglong2 b01 = pb[0], b23 = pb[1];
            cb[k][0] = b01.x; cb[k][1] = b01.y; cb[k][2] = b23.x; cb[k][3] = b23.y;
            m[k] = ok ? -1 : 0;
        }
        int tbase = (dy + 1) * 3;
#pragma unroll
        for (int dx = 0; dx < 3; dx++) {
            int t = tbase + dx;
            nv0 -= m[dx]; nv1 -= m[dx + 1];
#pragma unroll
            for (int co = 0; co < 16; co++) {
                const u64* wp = &sw[(((g << 4) + co) * 9 + t) * 4];
                u64 w0 = wp[0], w1_ = wp[1], w2_ = wp[2], w3_ = wp[3];
#pragma unroll
                for (int p = 0; p < 2; p++) {
                    int k = dx + p;
                    int pt = __popcll(cb[k][0] ^ w0) + __popcll(cb[k][1] ^ w1_)
                           + __popcll(cb[k][2] ^ w2_) + __popcll(cb[k][3] ^ w3_);
                    acc[co][p] += pt & m[k];
                }
            }
        }
    }

    unsigned sb0 = 0, sb1 = 0;
    bool wr = (q < 2);
#pragma unroll
    for (int co = 0; co < 16; co++) {
        int col = (g << 4) + co;
        int coG = cobase + col;
        float A = sA[col], B = sB[col];
        float2 xr = *(const float2*)(x + (size_t)(b * 512 + coG) * HWSZ + hw);
        float v0 = (float)((nv0 << 8) - 2 * acc[co][0]) * A + B + xr.x;
        float v1 = (float)((nv1 << 8) - 2 * acc[co][1]) * A + B + xr.y;
        sb0 |= (unsigned)(v0 >= 0.f) << co;
        sb1 |= (unsigned)(v1 >= 0.f) << co;
        if (wr) {
            *(float2*)(c1v + (size_t)coG * NPIX + pix0) = make_float2(clampf(v0), clampf(v1));
        }
    }
    spart[g][lane * 2]     = (u16)sb0;
    spart[g][lane * 2 + 1] = (u16)sb1;
    __syncthreads();
    if (g == 0) {
#pragma unroll
        for (int p = 0; p < 2; p++) {
            int pi = lane * 2 + p;
            u64 word = (u64)spart[0][pi] | ((u64)spart[1][pi] << 16)
                     | ((u64)spart[2][pi] << 32) | ((u64)spart[3][pi] << 48);
            bitsC[(size_t)(pix0 + p) * 4 + q] = word;
        }
    }
}

// ---------------- conv2: 512->256 binary conv + bn + shuffled residual + clip ----------------
__global__ __launch_bounds__(256, 3) void k_conv2(
    const float* __restrict__ x, const float* __restrict__ mb,
    const u64* __restrict__ bitsC, const u64* __restrict__ bitsI,
    const u64* __restrict__ w2e, const u64* __restrict__ w2o,
    const float* __restrict__ A2, const float* __restrict__ B2,
    const float* __restrict__ c1v, float* __restrict__ out)
{
    __shared__ u64 se[2304], so[2304];
    __shared__ float sA[64], sB[64], sM[32];
    int tid = threadIdx.x;
    int q = blockIdx.y;
    int cobase = q * 64;
    {
        const u64* srcE = w2e + (size_t)cobase * 36;
        const u64* srcO = w2o + (size_t)cobase * 36;
#pragma unroll
        for (int i = 0; i < 9; i++) { se[tid + i * 256] = srcE[tid + i * 256]; so[tid + i * 256] = srcO[tid + i * 256]; }
        if (tid < 64) { sA[tid] = A2[cobase + tid]; sB[tid] = B2[cobase + tid]; }
        if (tid < 32) { sM[tid] = mb[q * 32 + tid]; }
    }
    __syncthreads();

    int g = tid >> 6, lane = tid & 63;
    int pix0 = blockIdx.x * 128 + lane * 2;
    int b = pix0 / HWSZ, hw = pix0 % HWSZ;
    int h = hw / WD, w = hw % WD;

    int acc[16][2];
#pragma unroll
    for (int co = 0; co < 16; co++) { acc[co][0] = 0; acc[co][1] = 0; }
    int nv0 = 0, nv1 = 0;

#pragma unroll 1
    for (int dy = -1; dy <= 1; dy++) {
        bool rowok = ((unsigned)(h + dy)) < (unsigned)WD;
        u64 cb[4][4], ib[4][4];
        int m[4];
#pragma unroll
        for (int k = 0; k < 4; k++) {
            int c = w - 1 + k;
            bool ok = rowok && ((unsigned)c < (unsigned)WD);
            int pg = pix0 + dy * WD + (k - 1);
            pg = pg < 0 ? 0 : (pg > NPIX - 1 ? NPIX - 1 : pg);
            const ulonglong2* pc = (const ulonglong2*)(bitsC + (size_t)pg * 4);
            const ulonglong2* pi = (const ulonglong2*)(bitsI + (size_t)pg * 4);
            ulonglong2 c01 = pc[0], c23 = pc[1];
            ulonglong2 i01 = pi[0], i23 = pi[1];
            cb[k][0] = c01.x; cb[k][1] = c01.y; cb[k][2] = c23.x; cb[k][3] = c23.y;
            ib[k][0] = i01.x; ib[k][1] = i01.y; ib[k][2] = i23.x; ib[k][3] = i23.y;
            m[k] = ok ? -1 : 0;
        }
        int tbase = (dy + 1) * 3;
#pragma unroll
        for (int dx = 0; dx < 3; dx++) {
            int t = tbase + dx;
            nv0 -= m[dx]; nv1 -= m[dx + 1];
#pragma unroll
            for (int co = 0; co < 16; co++) {
                const u64* we = &se[(((g << 4) + co) * 9 + t) * 4];
                const u64* wo = &so[(((g << 4) + co) * 9 + t) * 4];
                u64 e0 = we[0], e1 = we[1], e2 = we[2], e3 = we[3];
                u64 o0 = wo[0], o1 = wo[1], o2 = wo[2], o3 = wo[3];
#pragma unroll
                for (int p = 0; p < 2; p++) {
                    int k = dx + p;
                    int pt = __popcll(cb[k][0] ^ e0) + __popcll(cb[k][1] ^ e1)
                           + __popcll(cb[k][2] ^ e2) + __popcll(cb[k][3] ^ e3)
                           + __popcll(ib[k][0] ^ o0) + __popcll(ib[k][1] ^ o1)
                           + __popcll(ib[k][2] ^ o2) + __popcll(ib[k][3] ^ o3);
                    acc[co][p] += pt & m[k];
                }
            }
        }
    }

#pragma unroll
    for (int co = 0; co < 16; co++) {
        int col = (g << 4) + co;
        int coG = cobase + col;
        int cg2 = coG >> 1;
        float A = sA[col], B = sB[col];
        float v0 = (float)((nv0 << 9) - 2 * acc[co][0]) * A + B;
        float v1 = (float)((nv1 << 9) - 2 * acc[co][1]) * A + B;
        float r0, r1;
        if ((co & 1) == 0) {   // coG even (cobase, g<<4 both even)
            float2 cv = *(const float2*)(c1v + (size_t)cg2 * NPIX + pix0);
            r0 = cv.x; r1 = cv.y;
        } else {
            float2 xi = *(const float2*)(x + (size_t)(b * 512 + 256 + cg2) * HWSZ + hw);
            float mbv = sM[col >> 1];
            r0 = xi.x + mbv; r1 = xi.y + mbv;
        }
        *(float2*)(out + (size_t)(b * 256 + coG) * HWSZ + hw) =
            make_float2(clampf(v0 + r0), clampf(v1 + r1));
    }
}

extern "C" void kernel_launch(void* const* d_in, const int* in_sizes, int n_in,
                              void* d_out, int out_size, void* d_ws, size_t ws_size,
                              hipStream_t stream)
{
    const float* x   = (const float*)d_in[0];
    const float* w1  = (const float*)d_in[1];
    const float* w2  = (const float*)d_in[2];
    const float* g1  = (const float*)d_in[3];
    const float* be1 = (const float*)d_in[4];
    const float* m1  = (const float*)d_in[5];
    const float* v1  = (const float*)d_in[6];
    const float* g2  = (const float*)d_in[7];
    const float* be2 = (const float*)d_in[8];
    const float* m2  = (const float*)d_in[9];
    const float* v2  = (const float*)d_in[10];
    const float* mb  = (const float*)d_in[11];

    char* ws = (char*)d_ws;
    u64* w1b = (u64*)ws; ws += 73728;
    u64* w2e = (u64*)ws; ws += 73728;
    u64* w2o = (u64*)ws; ws += 73728;
    float* A1 = (float*)ws; ws += 1024;
    float* B1 = (float*)ws; ws += 1024;
    float* A2 = (float*)ws; ws += 1024;
    float* B2 = (float*)ws; ws += 1024;
    u64* bitsA = (u64*)ws; ws += (size_t)NPIX * 4 * 8;
    u64* bitsI = (u64*)ws; ws += (size_t)NPIX * 4 * 8;
    u64* bitsC = (u64*)ws; ws += (size_t)NPIX * 4 * 8;
    float* c1v = (float*)ws; ws += (size_t)128 * NPIX * 4;

    hipLaunchKernelGGL(k_wprep, dim3(256), dim3(256), 0, stream,
                       w1, w2, g1, be1, m1, v1, g2, be2, m2, v2,
                       w1b, w2e, w2o, A1, B1, A2, B2);
    hipLaunchKernelGGL(k_pack, dim3(196, 4), dim3(256), 0, stream, x, mb, bitsA, bitsI);
    hipLaunchKernelGGL(k_conv1, dim3(392, 4), dim3(256), 0, stream,
                       x, bitsA, w1b, A1, B1, bitsC, c1v);
    hipLaunchKernelGGL(k_conv2, dim3(392, 4), dim3(256), 0, stream,
                       x, mb, bitsC, bitsI, w2e, w2o, A2, B2, c1v, (float*)d_out);
}